// Round 1
// baseline (1033.417 us; speedup 1.0000x reference)
//
#include <hip/hip_runtime.h>

typedef short bf16x8 __attribute__((ext_vector_type(8)));
typedef float f32x4 __attribute__((ext_vector_type(4)));

// ---------- helpers ----------
__device__ __forceinline__ ushort f2bf(float f) {
  union { float f; unsigned u; } x; x.f = f;
  unsigned r = x.u + 0x7fffu + ((x.u >> 16) & 1u);  // RNE
  return (ushort)(r >> 16);
}
__device__ __forceinline__ float bf2f(ushort u) {
  union { unsigned u; float f; } x; x.u = ((unsigned)u) << 16; return x.f;
}
__device__ __forceinline__ void load_lds16(const void* g, void* l) {
  __builtin_amdgcn_global_load_lds((const __attribute__((address_space(1))) void*)g,
                                   (__attribute__((address_space(3))) void*)l, 16, 0, 0);
}
__device__ __forceinline__ void store_out(float* p, float v) { *p = v; }
__device__ __forceinline__ void store_out(ushort* p, float v) { *p = f2bf(v); }

// ---------- fp32 -> bf16 cast ----------
__global__ __launch_bounds__(256) void cast_kernel(const float* __restrict__ in,
                                                   ushort* __restrict__ out, int n4) {
  int i = blockIdx.x * 256 + threadIdx.x;
  if (i < n4) {
    float4 v = ((const float4*)in)[i];
    ushort4 o;
    o.x = f2bf(v.x); o.y = f2bf(v.y); o.z = f2bf(v.z); o.w = f2bf(v.w);
    ((ushort4*)out)[i] = o;
  }
}

// ---------- NT GEMM: C[M,N] = A[M,K] * B[N,K]^T, bf16 in, fp32 acc ----------
// 128x128 tile, BK=32, 256 thr = 4 waves (2x2), each wave 4x4 of 16x16x32 MFMA.
template <typename OutT>
__global__ __launch_bounds__(256) void gemm_bt(const ushort* __restrict__ A,
                                               const ushort* __restrict__ B,
                                               OutT* __restrict__ C,
                                               int M, int N, int K) {
  __shared__ ushort As[128 * 32];
  __shared__ ushort Bs[128 * 32];
  const int tid = threadIdx.x;
  const int wave = tid >> 6, lane = tid & 63;
  const int quad = lane >> 4, lx = lane & 15;
  const int m0 = blockIdx.y * 128, n0 = blockIdx.x * 128;
  const int wr = wave >> 1, wc = wave & 1;
  const int srow = lane >> 2;        // staging: row within 16-row group
  const int scol = (lane & 3) * 8;   // staging: k elem offset (16B chunk)

  f32x4 acc[4][4] = {};

  for (int k0 = 0; k0 < K; k0 += 32) {
    __syncthreads();   // prior-iter LDS reads done before overwrite
#pragma unroll
    for (int p = 0; p < 2; ++p) {
      const int rg = (wave * 2 + p) * 16;
      load_lds16(A + (size_t)(m0 + rg + srow) * K + k0 + scol, As + rg * 32);
      load_lds16(B + (size_t)(n0 + rg + srow) * K + k0 + scol, Bs + rg * 32);
    }
    __syncthreads();   // staging visible (drains vmcnt)
    bf16x8 af[4], bfr[4];
#pragma unroll
    for (int i = 0; i < 4; ++i)
      af[i] = *(const bf16x8*)(As + (wr * 64 + i * 16 + lx) * 32 + quad * 8);
#pragma unroll
    for (int j = 0; j < 4; ++j)
      bfr[j] = *(const bf16x8*)(Bs + (wc * 64 + j * 16 + lx) * 32 + quad * 8);
#pragma unroll
    for (int i = 0; i < 4; ++i)
#pragma unroll
      for (int j = 0; j < 4; ++j)
        acc[i][j] = __builtin_amdgcn_mfma_f32_16x16x32_bf16(af[i], bfr[j], acc[i][j], 0, 0, 0);
  }
  // epilogue: C/D layout col=lane&15, row=quad*4+reg (m89-verified)
#pragma unroll
  for (int i = 0; i < 4; ++i)
#pragma unroll
    for (int j = 0; j < 4; ++j)
#pragma unroll
      for (int r = 0; r < 4; ++r) {
        const int row = m0 + wr * 64 + i * 16 + quad * 4 + r;
        const int col = n0 + wc * 64 + j * 16 + lx;
        store_out(C + (size_t)row * N + col, acc[i][j][r]);
      }
}

// ---------- RoPE in-place on bf16 qkv ----------
__global__ __launch_bounds__(256) void rope_kernel(const int* __restrict__ pos,
                                                   ushort* __restrict__ qkv) {
  const int rid = blockIdx.x * 4 + (threadIdx.x >> 6);  // 0 .. 163839 (t, 40 heads)
  const int d = threadIdx.x & 63;
  const int t = rid / 40;
  const int hh = rid - t * 40;
  ushort* p = qkv + (size_t)t * 6144 + (hh < 32 ? hh * 128 : 4096 + (hh - 32) * 128);
  const float inv_freq = powf(10000.0f, -(float)d * (1.0f / 64.0f));
  const float fr = (float)pos[t] * inv_freq;
  float sn, cs;
  sincosf(fr, &sn, &cs);
  const float x1 = bf2f(p[d]);
  const float x2 = bf2f(p[d + 64]);
  p[d] = f2bf(x1 * cs - x2 * sn);
  p[d + 64] = f2bf(x2 * cs + x1 * sn);
}

// ---------- fused flash attention (bf16 MFMA, causal GQA) ----------
// grid: 1024 = B(4) * H(32) * QB(8); block 256 = 4 waves, wave owns 32 q rows.
__global__ __launch_bounds__(256) void attn_fused(const ushort* __restrict__ qkv,
                                                  ushort* __restrict__ outb) {
  const int bid = blockIdx.x;
  const int qb = bid & 7;
  const int h = (bid >> 3) & 31;
  const int b = bid >> 8;
  const int kvh = h >> 2;                  // G = 4
  const int tid = threadIdx.x, wave = tid >> 6, lane = tid & 63;
  const int quad = lane >> 4, lx = lane & 15;

  __shared__ ushort Ks[64 * 128];   // [key][d]
  __shared__ ushort Vt[128 * 64];   // [d][key]  (transposed for PV B-frags)
  __shared__ ushort Ps[128 * 64];   // [qrow][key] (P round-trip, wave-private rows)

  const int qrow0 = qb * 128 + wave * 32;  // wave's first q row in sequence
  const size_t tb = (size_t)b * 1024;

  // Q fragments live in registers for the whole kernel (A-layout, m120-verified)
  bf16x8 qf[2][4];
#pragma unroll
  for (int qt = 0; qt < 2; ++qt)
#pragma unroll
    for (int ks = 0; ks < 4; ++ks)
      qf[qt][ks] = *(const bf16x8*)(qkv + (tb + qrow0 + qt * 16 + lx) * 6144 +
                                    h * 128 + ks * 32 + quad * 8);

  f32x4 o[2][8] = {};
  float mst[2][4], lst[2][4];
#pragma unroll
  for (int qt = 0; qt < 2; ++qt)
#pragma unroll
    for (int r = 0; r < 4; ++r) { mst[qt][r] = -1e30f; lst[qt][r] = 0.f; }

  const int nkt = 2 * (qb + 1);
  for (int it = 0; it < nkt; ++it) {
    const int kb = it * 64;
    __syncthreads();  // prior-iter K/V/P reads complete
    // stage K tile [64][128] via async global->LDS (4 x 1KB instr per wave)
#pragma unroll
    for (int i = 0; i < 4; ++i) {
      const int rg = wave * 16 + i * 4;
      load_lds16(qkv + (tb + kb + rg + quad) * 6144 + 4096 + kvh * 128 + lx * 8,
                 Ks + rg * 128);
    }
    // stage V transposed: thread key = lane, d-range = wave*32..+31 (bank-clean writes)
    {
      const ushort* vp = qkv + (tb + kb + lane) * 6144 + 5120 + kvh * 128 + wave * 32;
#pragma unroll
      for (int c = 0; c < 4; ++c) {
        bf16x8 v8 = *(const bf16x8*)(vp + c * 8);
#pragma unroll
        for (int e = 0; e < 8; ++e)
          Vt[(wave * 32 + c * 8 + e) * 64 + lane] = (ushort)v8[e];
      }
    }
    __syncthreads();

    // S = Q K^T  (2 qt x 4 kt tiles, 4 k-steps of 32)
    f32x4 s[2][4] = {};
#pragma unroll
    for (int ks = 0; ks < 4; ++ks) {
      bf16x8 kf[4];
#pragma unroll
      for (int kt = 0; kt < 4; ++kt)
        kf[kt] = *(const bf16x8*)(Ks + (kt * 16 + lx) * 128 + ks * 32 + quad * 8);
#pragma unroll
      for (int qt = 0; qt < 2; ++qt)
#pragma unroll
        for (int kt = 0; kt < 4; ++kt)
          s[qt][kt] = __builtin_amdgcn_mfma_f32_16x16x32_bf16(qf[qt][ks], kf[kt], s[qt][kt], 0, 0, 0);
    }

    // online softmax, row stats via 16-lane shfl groups
    const float scale = 0.08838834764831843f;  // 1/sqrt(128)
    const bool diag = (kb + 63 > qrow0);
#pragma unroll
    for (int qt = 0; qt < 2; ++qt) {
#pragma unroll
      for (int r = 0; r < 4; ++r) {
        const int row = qrow0 + qt * 16 + quad * 4 + r;
        float mx = -1e30f;
#pragma unroll
        for (int kt = 0; kt < 4; ++kt) {
          float sv = s[qt][kt][r] * scale;
          if (diag && (kb + kt * 16 + lx > row)) sv = -1e30f;
          s[qt][kt][r] = sv;
          mx = fmaxf(mx, sv);
        }
        mx = fmaxf(mx, __shfl_xor(mx, 1));
        mx = fmaxf(mx, __shfl_xor(mx, 2));
        mx = fmaxf(mx, __shfl_xor(mx, 4));
        mx = fmaxf(mx, __shfl_xor(mx, 8));
        const float mnew = fmaxf(mst[qt][r], mx);
        const float alpha = __expf(mst[qt][r] - mnew);
        mst[qt][r] = mnew;
        float rs = 0.f;
#pragma unroll
        for (int kt = 0; kt < 4; ++kt) {
          const float pv = __expf(s[qt][kt][r] - mnew);
          s[qt][kt][r] = pv;
          rs += pv;
        }
        rs += __shfl_xor(rs, 1); rs += __shfl_xor(rs, 2);
        rs += __shfl_xor(rs, 4); rs += __shfl_xor(rs, 8);
        lst[qt][r] = lst[qt][r] * alpha + rs;
#pragma unroll
        for (int dt = 0; dt < 8; ++dt) o[qt][dt][r] *= alpha;
#pragma unroll
        for (int kt = 0; kt < 4; ++kt)
          Ps[(wave * 32 + qt * 16 + quad * 4 + r) * 64 + kt * 16 + lx] = f2bf(s[qt][kt][r]);
      }
    }
    __syncthreads();  // P visible (conservative; rows are wave-private)

    // O += P V  (A = P from LDS in A-layout, B = Vt rows)
#pragma unroll
    for (int ks2 = 0; ks2 < 2; ++ks2) {
      bf16x8 pf[2];
#pragma unroll
      for (int qt = 0; qt < 2; ++qt)
        pf[qt] = *(const bf16x8*)(Ps + (wave * 32 + qt * 16 + lx) * 64 + ks2 * 32 + quad * 8);
#pragma unroll
      for (int dt = 0; dt < 8; ++dt) {
        bf16x8 vf = *(const bf16x8*)(Vt + (dt * 16 + lx) * 64 + ks2 * 32 + quad * 8);
#pragma unroll
        for (int qt = 0; qt < 2; ++qt)
          o[qt][dt] = __builtin_amdgcn_mfma_f32_16x16x32_bf16(pf[qt], vf, o[qt][dt], 0, 0, 0);
      }
    }
  }

  // epilogue: O /= l, store bf16 [T][H*D]
#pragma unroll
  for (int qt = 0; qt < 2; ++qt)
#pragma unroll
    for (int r = 0; r < 4; ++r) {
      const float inv = 1.f / lst[qt][r];
      const int row = qrow0 + qt * 16 + quad * 4 + r;
#pragma unroll
      for (int dt = 0; dt < 8; ++dt)
        outb[(tb + row) * 4096 + h * 128 + dt * 16 + lx] = f2bf(o[qt][dt][r] * inv);
    }
}

// ---------- launch ----------
extern "C" void kernel_launch(void* const* d_in, const int* in_sizes, int n_in,
                              void* d_out, int out_size, void* d_ws, size_t ws_size,
                              hipStream_t stream) {
  const int* positions = (const int*)d_in[0];
  const float* hidden  = (const float*)d_in[1];
  const float* w_qkv   = (const float*)d_in[2];
  const float* w_dense = (const float*)d_in[3];
  float* out = (float*)d_out;

  // workspace layout (ushorts): 192 MiB total
  ushort* hidden_bf = (ushort*)d_ws;                         // 4096*4096
  ushort* wqkv_bf   = hidden_bf + (size_t)16777216;          // 6144*4096
  ushort* wdense_bf = wqkv_bf   + (size_t)25165824;          // 4096*4096
  ushort* qkv_bf    = wdense_bf + (size_t)16777216;          // 4096*6144
  ushort* attn_bf   = qkv_bf    + (size_t)25165824;          // 4096*4096

  cast_kernel<<<16384, 256, 0, stream>>>(hidden,  hidden_bf, 4194304);
  cast_kernel<<<24576, 256, 0, stream>>>(w_qkv,   wqkv_bf,   6291456);
  cast_kernel<<<16384, 256, 0, stream>>>(w_dense, wdense_bf, 4194304);

  // qkv = hidden @ w_qkv^T  -> bf16 [4096][6144]
  gemm_bt<ushort><<<dim3(48, 32), 256, 0, stream>>>(hidden_bf, wqkv_bf, qkv_bf, 4096, 6144, 4096);

  // RoPE on q (32 heads) + k (8 heads), in place
  rope_kernel<<<40960, 256, 0, stream>>>(positions, qkv_bf);

  // fused causal GQA attention -> bf16 [4096][4096]
  attn_fused<<<1024, 256, 0, stream>>>(qkv_bf, attn_bf);

  // out = attn @ w_dense^T -> fp32
  gemm_bt<float><<<dim3(32, 32), 256, 0, stream>>>(attn_bf, wdense_bf, out, 4096, 4096, 4096);
}

// Round 2
// 866.804 us; speedup vs baseline: 1.1922x; 1.1922x over previous
//
#include <hip/hip_runtime.h>

typedef short bf16x8 __attribute__((ext_vector_type(8)));
typedef float f32x4 __attribute__((ext_vector_type(4)));

// ---------- helpers ----------
__device__ __forceinline__ ushort f2bf(float f) {
  union { float f; unsigned u; } x; x.f = f;
  unsigned r = x.u + 0x7fffu + ((x.u >> 16) & 1u);  // RNE
  return (ushort)(r >> 16);
}
__device__ __forceinline__ float bf2f(ushort u) {
  union { unsigned u; float f; } x; x.u = ((unsigned)u) << 16; return x.f;
}
__device__ __forceinline__ void load_lds16(const void* g, void* l) {
  __builtin_amdgcn_global_load_lds((const __attribute__((address_space(1))) void*)g,
                                   (__attribute__((address_space(3))) void*)l, 16, 0, 0);
}
__device__ __forceinline__ void store_out(float* p, float v) { *p = v; }
__device__ __forceinline__ void store_out(ushort* p, float v) { *p = f2bf(v); }

// ---------- fp32 -> bf16 cast ----------
__global__ __launch_bounds__(256) void cast_kernel(const float* __restrict__ in,
                                                   ushort* __restrict__ out, int n4) {
  int i = blockIdx.x * 256 + threadIdx.x;
  if (i < n4) {
    float4 v = ((const float4*)in)[i];
    ushort4 o;
    o.x = f2bf(v.x); o.y = f2bf(v.y); o.z = f2bf(v.z); o.w = f2bf(v.w);
    ((ushort4*)out)[i] = o;
  }
}

// ---------- NT GEMM: C[M,N] = A[M,K] * B[N,K]^T, bf16 in, fp32 acc ----------
// 128x128 tile, BK=32, 4 waves 2x2, 4x4 of 16x16x32 MFMA.
// LDS rows are XOR-swizzled at 16B-chunk granularity: LDS[r][c] = G[r][c ^ ((r>>1)&3)]
// -> b128 frag reads go from 8-way to 2-way (free) bank aliasing.
template <typename OutT>
__global__ __launch_bounds__(256) void gemm_bt(const ushort* __restrict__ A,
                                               const ushort* __restrict__ B,
                                               OutT* __restrict__ C,
                                               int M, int N, int K) {
  __shared__ ushort As[128 * 32];
  __shared__ ushort Bs[128 * 32];
  const int tid = threadIdx.x;
  const int wave = tid >> 6, lane = tid & 63;
  const int quad = lane >> 4, lx = lane & 15;
  const int m0 = blockIdx.y * 128, n0 = blockIdx.x * 128;
  const int wr = wave >> 1, wc = wave & 1;
  const int srow = lane >> 2;                                   // row within 16-row group
  const int scol = ((lane & 3) ^ ((lane >> 3) & 3)) * 8;        // swizzled k-chunk
  const int rchunk = (quad ^ ((lx >> 1) & 3)) * 8;              // swizzled read chunk

  f32x4 acc[4][4] = {};

  for (int k0 = 0; k0 < K; k0 += 32) {
    __syncthreads();
#pragma unroll
    for (int p = 0; p < 2; ++p) {
      const int rg = (wave * 2 + p) * 16;
      load_lds16(A + (size_t)(m0 + rg + srow) * K + k0 + scol, As + rg * 32);
      load_lds16(B + (size_t)(n0 + rg + srow) * K + k0 + scol, Bs + rg * 32);
    }
    __syncthreads();
    bf16x8 af[4], bfr[4];
#pragma unroll
    for (int i = 0; i < 4; ++i)
      af[i] = *(const bf16x8*)(As + (wr * 64 + i * 16 + lx) * 32 + rchunk);
#pragma unroll
    for (int j = 0; j < 4; ++j)
      bfr[j] = *(const bf16x8*)(Bs + (wc * 64 + j * 16 + lx) * 32 + rchunk);
#pragma unroll
    for (int i = 0; i < 4; ++i)
#pragma unroll
      for (int j = 0; j < 4; ++j)
        acc[i][j] = __builtin_amdgcn_mfma_f32_16x16x32_bf16(af[i], bfr[j], acc[i][j], 0, 0, 0);
  }
#pragma unroll
  for (int i = 0; i < 4; ++i)
#pragma unroll
    for (int j = 0; j < 4; ++j)
#pragma unroll
      for (int r = 0; r < 4; ++r) {
        const int row = m0 + wr * 64 + i * 16 + quad * 4 + r;
        const int col = n0 + wc * 64 + j * 16 + lx;
        store_out(C + (size_t)row * N + col, acc[i][j][r]);
      }
}

// ---------- RoPE in-place on bf16 qkv ----------
__global__ __launch_bounds__(256) void rope_kernel(const int* __restrict__ pos,
                                                   ushort* __restrict__ qkv) {
  const int rid = blockIdx.x * 4 + (threadIdx.x >> 6);
  const int d = threadIdx.x & 63;
  const int t = rid / 40;
  const int hh = rid - t * 40;
  ushort* p = qkv + (size_t)t * 6144 + (hh < 32 ? hh * 128 : 4096 + (hh - 32) * 128);
  const float inv_freq = powf(10000.0f, -(float)d * (1.0f / 64.0f));
  const float fr = (float)pos[t] * inv_freq;
  float sn, cs;
  sincosf(fr, &sn, &cs);
  const float x1 = bf2f(p[d]);
  const float x2 = bf2f(p[d + 64]);
  p[d] = f2bf(x1 * cs - x2 * sn);
  p[d + 64] = f2bf(x2 * cs + x1 * sn);
}

// ---------- fused flash attention (bf16 MFMA, causal GQA) ----------
// grid: 1024 = B(4) * H(32) * PAIR(8). Block = 256 thr = 4 waves.
// Block processes q-tiles (pair) and (15-pair) of 64 rows -> 17 k-tiles each,
// perfectly balanced. Wave owns 16 q rows. LDS XOR-swizzled (chunk ^= row&7).
__global__ __launch_bounds__(256) void attn_fused(const ushort* __restrict__ qkv,
                                                  ushort* __restrict__ outb) {
  const int bid = blockIdx.x;
  const int pair = bid & 7;
  const int h = (bid >> 3) & 31;
  const int b = bid >> 8;
  const int kvh = h >> 2;                  // G = 4
  const int tid = threadIdx.x, wave = tid >> 6, lane = tid & 63;
  const int quad = lane >> 4, lx = lane & 15;

  __shared__ ushort Ks[64 * 128];   // [key][d], chunk ^= key&7
  __shared__ ushort Vt[128 * 64];   // [d][key], chunk ^= d&7
  __shared__ ushort Ps[64 * 64];    // [qrow][key], chunk ^= qrow&7

  const size_t tb = (size_t)b * 1024;
  const float scale = 0.08838834764831843f;  // 1/sqrt(128)

#pragma unroll
  for (int phase = 0; phase < 2; ++phase) {
    const int qt64 = phase ? (15 - pair) : pair;
    const int qrow0 = qt64 * 64 + wave * 16;

    // Q fragments (A-layout) live in registers for the phase
    bf16x8 qf[4];
#pragma unroll
    for (int ks = 0; ks < 4; ++ks)
      qf[ks] = *(const bf16x8*)(qkv + (tb + qrow0 + lx) * 6144 + h * 128 + ks * 32 + quad * 8);

    f32x4 o[8] = {};
    float mst[4], lst[4];
#pragma unroll
    for (int r = 0; r < 4; ++r) { mst[r] = -1e30f; lst[r] = 0.f; }

    const int nkt = qt64 + 1;
    for (int it = 0; it < nkt; ++it) {
      const int kb = it * 64;
      __syncthreads();  // prior-iter / prior-phase LDS reads complete
      // stage K [64][128] via async global->LDS, source chunk XOR-swizzled so
      // the linear lane->LDS placement realizes LDS[r][c] = K[r][c ^ (r&7)]
#pragma unroll
      for (int i = 0; i < 4; ++i) {
        const int rg = wave * 16 + i * 4;
        const int row = rg + quad;
        load_lds16(qkv + (tb + kb + row) * 6144 + 4096 + kvh * 128 + ((lx ^ (row & 7)) * 8),
                   Ks + rg * 128);
      }
      // stage V transposed: lane = key, wave covers d in [wave*32, +32)
      {
        const ushort* vp = qkv + (tb + kb + lane) * 6144 + 5120 + kvh * 128 + wave * 32;
#pragma unroll
        for (int c = 0; c < 4; ++c) {
          bf16x8 v8 = *(const bf16x8*)(vp + c * 8);
#pragma unroll
          for (int e = 0; e < 8; ++e) {
            const int d = wave * 32 + c * 8 + e;
            Vt[d * 64 + (((lane >> 3) ^ (d & 7)) * 8) + (lane & 7)] = (ushort)v8[e];
          }
        }
      }
      __syncthreads();

      // S = Q K^T : 4 kt tiles x 4 k-steps
      f32x4 s[4] = {};
#pragma unroll
      for (int ks = 0; ks < 4; ++ks) {
        bf16x8 kf[4];
#pragma unroll
        for (int kt = 0; kt < 4; ++kt)
          kf[kt] = *(const bf16x8*)(Ks + (kt * 16 + lx) * 128 + (((ks * 4 + quad) ^ (lx & 7)) * 8));
#pragma unroll
        for (int kt = 0; kt < 4; ++kt)
          s[kt] = __builtin_amdgcn_mfma_f32_16x16x32_bf16(qf[ks], kf[kt], s[kt], 0, 0, 0);
      }

      // online softmax; row stats across the 16 lanes of each quad-row group
      const bool diag = (kb + 63 > qrow0);
#pragma unroll
      for (int r = 0; r < 4; ++r) {
        const int row = qrow0 + quad * 4 + r;
        float mx = -1e30f;
#pragma unroll
        for (int kt = 0; kt < 4; ++kt) {
          float sv = s[kt][r] * scale;
          if (diag && (kb + kt * 16 + lx > row)) sv = -1e30f;
          s[kt][r] = sv;
          mx = fmaxf(mx, sv);
        }
        mx = fmaxf(mx, __shfl_xor(mx, 1));
        mx = fmaxf(mx, __shfl_xor(mx, 2));
        mx = fmaxf(mx, __shfl_xor(mx, 4));
        mx = fmaxf(mx, __shfl_xor(mx, 8));
        const float mnew = fmaxf(mst[r], mx);
        const float alpha = __expf(mst[r] - mnew);
        mst[r] = mnew;
        float rs = 0.f;
#pragma unroll
        for (int kt = 0; kt < 4; ++kt) {
          const float pv = __expf(s[kt][r] - mnew);
          s[kt][r] = pv;
          rs += pv;
        }
        rs += __shfl_xor(rs, 1); rs += __shfl_xor(rs, 2);
        rs += __shfl_xor(rs, 4); rs += __shfl_xor(rs, 8);
        lst[r] = lst[r] * alpha + rs;
#pragma unroll
        for (int dt = 0; dt < 8; ++dt) o[dt][r] *= alpha;
        const int prow = wave * 16 + quad * 4 + r;
#pragma unroll
        for (int kt = 0; kt < 4; ++kt)
          Ps[prow * 64 + (((kt * 2 + (lx >> 3)) ^ (prow & 7)) * 8) + (lx & 7)] = f2bf(s[kt][r]);
      }
      __syncthreads();  // P visible

      // O += P V  (A = P rows from LDS, B = Vt rows)
#pragma unroll
      for (int ks2 = 0; ks2 < 2; ++ks2) {
        const int prow = wave * 16 + lx;  // prow&7 == lx&7
        bf16x8 pf = *(const bf16x8*)(Ps + prow * 64 + (((ks2 * 4 + quad) ^ (lx & 7)) * 8));
#pragma unroll
        for (int dt = 0; dt < 8; ++dt) {
          bf16x8 vf = *(const bf16x8*)(Vt + (dt * 16 + lx) * 64 + (((ks2 * 4 + quad) ^ (lx & 7)) * 8));
          o[dt] = __builtin_amdgcn_mfma_f32_16x16x32_bf16(pf, vf, o[dt], 0, 0, 0);
        }
      }
    }

    // epilogue: O /= l, store bf16 [T][H*D]
#pragma unroll
    for (int r = 0; r < 4; ++r) {
      const float inv = 1.f / lst[r];
      const int row = qrow0 + quad * 4 + r;
#pragma unroll
      for (int dt = 0; dt < 8; ++dt)
        outb[(tb + row) * 4096 + h * 128 + dt * 16 + lx] = f2bf(o[dt][r] * inv);
    }
  }
}

// ---------- launch ----------
extern "C" void kernel_launch(void* const* d_in, const int* in_sizes, int n_in,
                              void* d_out, int out_size, void* d_ws, size_t ws_size,
                              hipStream_t stream) {
  const int* positions = (const int*)d_in[0];
  const float* hidden  = (const float*)d_in[1];
  const float* w_qkv   = (const float*)d_in[2];
  const float* w_dense = (const float*)d_in[3];
  float* out = (float*)d_out;

  ushort* hidden_bf = (ushort*)d_ws;                         // 4096*4096
  ushort* wqkv_bf   = hidden_bf + (size_t)16777216;          // 6144*4096
  ushort* wdense_bf = wqkv_bf   + (size_t)25165824;          // 4096*4096
  ushort* qkv_bf    = wdense_bf + (size_t)16777216;          // 4096*6144
  ushort* attn_bf   = qkv_bf    + (size_t)25165824;          // 4096*4096

  cast_kernel<<<16384, 256, 0, stream>>>(hidden,  hidden_bf, 4194304);
  cast_kernel<<<24576, 256, 0, stream>>>(w_qkv,   wqkv_bf,   6291456);
  cast_kernel<<<16384, 256, 0, stream>>>(w_dense, wdense_bf, 4194304);

  gemm_bt<ushort><<<dim3(48, 32), 256, 0, stream>>>(hidden_bf, wqkv_bf, qkv_bf, 4096, 6144, 4096);

  rope_kernel<<<40960, 256, 0, stream>>>(positions, qkv_bf);

  attn_fused<<<1024, 256, 0, stream>>>(qkv_bf, attn_bf);

  gemm_bt<float><<<dim3(32, 32), 256, 0, stream>>>(attn_bf, wdense_bf, out, 4096, 4096, 4096);
}

// Round 3
// 788.078 us; speedup vs baseline: 1.3113x; 1.0999x over previous
//
#include <hip/hip_runtime.h>

typedef short bf16x8 __attribute__((ext_vector_type(8)));
typedef float f32x4 __attribute__((ext_vector_type(4)));
typedef float f32x16 __attribute__((ext_vector_type(16)));

// ---------- helpers ----------
__device__ __forceinline__ ushort f2bf(float f) {
  union { float f; unsigned u; } x; x.f = f;
  unsigned r = x.u + 0x7fffu + ((x.u >> 16) & 1u);  // RNE
  return (ushort)(r >> 16);
}
__device__ __forceinline__ float bf2f(ushort u) {
  union { unsigned u; float f; } x; x.u = ((unsigned)u) << 16; return x.f;
}
__device__ __forceinline__ void load_lds16(const void* g, void* l) {
  __builtin_amdgcn_global_load_lds((const __attribute__((address_space(1))) void*)g,
                                   (__attribute__((address_space(3))) void*)l, 16, 0, 0);
}
__device__ __forceinline__ void store_out(float* p, float v) { *p = v; }
__device__ __forceinline__ void store_out(ushort* p, float v) { *p = f2bf(v); }

// ---------- fp32 -> bf16 cast ----------
__global__ __launch_bounds__(256) void cast_kernel(const float* __restrict__ in,
                                                   ushort* __restrict__ out, int n4) {
  int i = blockIdx.x * 256 + threadIdx.x;
  if (i < n4) {
    float4 v = ((const float4*)in)[i];
    ushort4 o;
    o.x = f2bf(v.x); o.y = f2bf(v.y); o.z = f2bf(v.z); o.w = f2bf(v.w);
    ((ushort4*)out)[i] = o;
  }
}

// ---------- NT GEMM: C[M,N] = A[M,K] * B[N,K]^T, bf16 in, fp32 acc ----------
// 128x128 tile, BK=64, 4 waves 2x2, each wave 2x2 of mfma_f32_32x32x16_bf16.
// LDS[row][chunk] = G[row][chunk ^ (row&7)] (16B chunks) -> conflict-free b128 reads.
template <typename OutT>
__global__ __launch_bounds__(256) void gemm_bt(const ushort* __restrict__ A,
                                               const ushort* __restrict__ B,
                                               OutT* __restrict__ C,
                                               int M, int N, int K) {
  __shared__ ushort As[128 * 64];
  __shared__ ushort Bs[128 * 64];
  const int tid = threadIdx.x;
  const int wave = tid >> 6, lane = tid & 63;
  const int half = lane >> 5, l32 = lane & 31;
  const int m0 = blockIdx.y * 128, n0 = blockIdx.x * 128;
  const int wr = wave >> 1, wc = wave & 1;
  // staging: wave stages rows [wave*32, +32) of each array; 4 instrs x 8 rows.
  // LDS dest is linear (base + lane*16); source chunk is XOR-swizzled.
  const int sgrow = lane >> 3;                    // row within 8-row group = row&7
  const int sgchunk = ((lane & 7) ^ sgrow) * 8;   // swizzled global k-chunk (elems)

  f32x16 acc[2][2] = {};

  for (int k0 = 0; k0 < K; k0 += 64) {
    __syncthreads();
#pragma unroll
    for (int i = 0; i < 4; ++i) {
      const int rg = wave * 32 + i * 8;           // 8-row group base
      load_lds16(A + (size_t)(m0 + rg + sgrow) * K + k0 + sgchunk, As + rg * 64);
      load_lds16(B + (size_t)(n0 + rg + sgrow) * K + k0 + sgchunk, Bs + rg * 64);
    }
    __syncthreads();
#pragma unroll
    for (int s = 0; s < 4; ++s) {
      bf16x8 af[2], bfr[2];
#pragma unroll
      for (int i = 0; i < 2; ++i) {
        const int row = wr * 64 + i * 32 + l32;
        af[i] = *(const bf16x8*)(As + row * 64 + (((s * 2 + half) ^ (row & 7)) * 8));
      }
#pragma unroll
      for (int j = 0; j < 2; ++j) {
        const int row = wc * 64 + j * 32 + l32;
        bfr[j] = *(const bf16x8*)(Bs + row * 64 + (((s * 2 + half) ^ (row & 7)) * 8));
      }
#pragma unroll
      for (int i = 0; i < 2; ++i)
#pragma unroll
        for (int j = 0; j < 2; ++j)
          acc[i][j] = __builtin_amdgcn_mfma_f32_32x32x16_bf16(af[i], bfr[j], acc[i][j], 0, 0, 0);
    }
  }
  // epilogue: C/D layout col=lane&31, row=(reg&3)+8*(reg>>2)+4*(lane>>5) (m74/m101)
#pragma unroll
  for (int i = 0; i < 2; ++i)
#pragma unroll
    for (int j = 0; j < 2; ++j)
#pragma unroll
      for (int r = 0; r < 16; ++r) {
        const int row = m0 + wr * 64 + i * 32 + (r & 3) + 8 * (r >> 2) + 4 * half;
        const int col = n0 + wc * 64 + j * 32 + l32;
        store_out(C + (size_t)row * N + col, acc[i][j][r]);
      }
}

// ---------- RoPE in-place on bf16 qkv ----------
__global__ __launch_bounds__(256) void rope_kernel(const int* __restrict__ pos,
                                                   ushort* __restrict__ qkv) {
  const int rid = blockIdx.x * 4 + (threadIdx.x >> 6);
  const int d = threadIdx.x & 63;
  const int t = rid / 40;
  const int hh = rid - t * 40;
  ushort* p = qkv + (size_t)t * 6144 + (hh < 32 ? hh * 128 : 4096 + (hh - 32) * 128);
  const float inv_freq = powf(10000.0f, -(float)d * (1.0f / 64.0f));
  const float fr = (float)pos[t] * inv_freq;
  float sn, cs;
  sincosf(fr, &sn, &cs);
  const float x1 = bf2f(p[d]);
  const float x2 = bf2f(p[d + 64]);
  p[d] = f2bf(x1 * cs - x2 * sn);
  p[d + 64] = f2bf(x2 * cs + x1 * sn);
}

// ---------- fused flash attention (bf16 MFMA, causal GQA) ----------
// grid: 1024 = B(4) * H(32) * PAIR(8). Block = 256 thr = 4 waves.
// Block processes q-tiles (pair) and (15-pair) of 64 rows -> 17 k-tiles each.
__global__ __launch_bounds__(256) void attn_fused(const ushort* __restrict__ qkv,
                                                  ushort* __restrict__ outb) {
  const int bid = blockIdx.x;
  const int pair = bid & 7;
  const int h = (bid >> 3) & 31;
  const int b = bid >> 8;
  const int kvh = h >> 2;                  // G = 4
  const int tid = threadIdx.x, wave = tid >> 6, lane = tid & 63;
  const int quad = lane >> 4, lx = lane & 15;

  __shared__ ushort Ks[64 * 128];   // [key][d], chunk ^= key&7
  __shared__ ushort Vt[128 * 64];   // [d][key], chunk ^= d&7
  __shared__ ushort Ps[64 * 64];    // [qrow][key], chunk ^= qrow&7

  const size_t tb = (size_t)b * 1024;
  const float scale = 0.08838834764831843f;  // 1/sqrt(128)

#pragma unroll
  for (int phase = 0; phase < 2; ++phase) {
    const int qt64 = phase ? (15 - pair) : pair;
    const int qrow0 = qt64 * 64 + wave * 16;

    bf16x8 qf[4];
#pragma unroll
    for (int ks = 0; ks < 4; ++ks)
      qf[ks] = *(const bf16x8*)(qkv + (tb + qrow0 + lx) * 6144 + h * 128 + ks * 32 + quad * 8);

    f32x4 o[8] = {};
    float mst[4], lst[4];
#pragma unroll
    for (int r = 0; r < 4; ++r) { mst[r] = -1e30f; lst[r] = 0.f; }

    const int nkt = qt64 + 1;
    for (int it = 0; it < nkt; ++it) {
      const int kb = it * 64;
      __syncthreads();
#pragma unroll
      for (int i = 0; i < 4; ++i) {
        const int rg = wave * 16 + i * 4;
        const int row = rg + quad;
        load_lds16(qkv + (tb + kb + row) * 6144 + 4096 + kvh * 128 + ((lx ^ (row & 7)) * 8),
                   Ks + rg * 128);
      }
      {
        const ushort* vp = qkv + (tb + kb + lane) * 6144 + 5120 + kvh * 128 + wave * 32;
#pragma unroll
        for (int c = 0; c < 4; ++c) {
          bf16x8 v8 = *(const bf16x8*)(vp + c * 8);
#pragma unroll
          for (int e = 0; e < 8; ++e) {
            const int d = wave * 32 + c * 8 + e;
            Vt[d * 64 + (((lane >> 3) ^ (d & 7)) * 8) + (lane & 7)] = (ushort)v8[e];
          }
        }
      }
      __syncthreads();

      f32x4 s[4] = {};
#pragma unroll
      for (int ks = 0; ks < 4; ++ks) {
        bf16x8 kf[4];
#pragma unroll
        for (int kt = 0; kt < 4; ++kt)
          kf[kt] = *(const bf16x8*)(Ks + (kt * 16 + lx) * 128 + (((ks * 4 + quad) ^ (lx & 7)) * 8));
#pragma unroll
        for (int kt = 0; kt < 4; ++kt)
          s[kt] = __builtin_amdgcn_mfma_f32_16x16x32_bf16(qf[ks], kf[kt], s[kt], 0, 0, 0);
      }

      const bool diag = (kb + 63 > qrow0);
#pragma unroll
      for (int r = 0; r < 4; ++r) {
        const int row = qrow0 + quad * 4 + r;
        float mx = -1e30f;
#pragma unroll
        for (int kt = 0; kt < 4; ++kt) {
          float sv = s[kt][r] * scale;
          if (diag && (kb + kt * 16 + lx > row)) sv = -1e30f;
          s[kt][r] = sv;
          mx = fmaxf(mx, sv);
        }
        mx = fmaxf(mx, __shfl_xor(mx, 1));
        mx = fmaxf(mx, __shfl_xor(mx, 2));
        mx = fmaxf(mx, __shfl_xor(mx, 4));
        mx = fmaxf(mx, __shfl_xor(mx, 8));
        const float mnew = fmaxf(mst[r], mx);
        const float alpha = __expf(mst[r] - mnew);
        mst[r] = mnew;
        float rs = 0.f;
#pragma unroll
        for (int kt = 0; kt < 4; ++kt) {
          const float pv = __expf(s[kt][r] - mnew);
          s[kt][r] = pv;
          rs += pv;
        }
        rs += __shfl_xor(rs, 1); rs += __shfl_xor(rs, 2);
        rs += __shfl_xor(rs, 4); rs += __shfl_xor(rs, 8);
        lst[r] = lst[r] * alpha + rs;
#pragma unroll
        for (int dt = 0; dt < 8; ++dt) o[dt][r] *= alpha;
        const int prow = wave * 16 + quad * 4 + r;
#pragma unroll
        for (int kt = 0; kt < 4; ++kt)
          Ps[prow * 64 + (((kt * 2 + (lx >> 3)) ^ (prow & 7)) * 8) + (lx & 7)] = f2bf(s[kt][r]);
      }
      __syncthreads();

#pragma unroll
      for (int ks2 = 0; ks2 < 2; ++ks2) {
        const int prow = wave * 16 + lx;
        bf16x8 pf = *(const bf16x8*)(Ps + prow * 64 + (((ks2 * 4 + quad) ^ (lx & 7)) * 8));
#pragma unroll
        for (int dt = 0; dt < 8; ++dt) {
          bf16x8 vf = *(const bf16x8*)(Vt + (dt * 16 + lx) * 64 + (((ks2 * 4 + quad) ^ (lx & 7)) * 8));
          o[dt] = __builtin_amdgcn_mfma_f32_16x16x32_bf16(pf, vf, o[dt], 0, 0, 0);
        }
      }
    }

#pragma unroll
    for (int r = 0; r < 4; ++r) {
      const float inv = 1.f / lst[r];
      const int row = qrow0 + quad * 4 + r;
#pragma unroll
      for (int dt = 0; dt < 8; ++dt)
        outb[(tb + row) * 4096 + h * 128 + dt * 16 + lx] = f2bf(o[dt][r] * inv);
    }
  }
}

// ---------- launch ----------
extern "C" void kernel_launch(void* const* d_in, const int* in_sizes, int n_in,
                              void* d_out, int out_size, void* d_ws, size_t ws_size,
                              hipStream_t stream) {
  const int* positions = (const int*)d_in[0];
  const float* hidden  = (const float*)d_in[1];
  const float* w_qkv   = (const float*)d_in[2];
  const float* w_dense = (const float*)d_in[3];
  float* out = (float*)d_out;

  ushort* hidden_bf = (ushort*)d_ws;                         // 4096*4096
  ushort* wqkv_bf   = hidden_bf + (size_t)16777216;          // 6144*4096
  ushort* wdense_bf = wqkv_bf   + (size_t)25165824;          // 4096*4096
  ushort* qkv_bf    = wdense_bf + (size_t)16777216;          // 4096*6144
  ushort* attn_bf   = qkv_bf    + (size_t)25165824;          // 4096*4096

  cast_kernel<<<16384, 256, 0, stream>>>(hidden,  hidden_bf, 4194304);
  cast_kernel<<<24576, 256, 0, stream>>>(w_qkv,   wqkv_bf,   6291456);
  cast_kernel<<<16384, 256, 0, stream>>>(w_dense, wdense_bf, 4194304);

  gemm_bt<ushort><<<dim3(48, 32), 256, 0, stream>>>(hidden_bf, wqkv_bf, qkv_bf, 4096, 6144, 4096);

  rope_kernel<<<40960, 256, 0, stream>>>(positions, qkv_bf);

  attn_fused<<<1024, 256, 0, stream>>>(qkv_bf, attn_bf);

  gemm_bt<float><<<dim3(32, 32), 256, 0, stream>>>(attn_bf, wdense_bf, out, 4096, 4096, 4096);
}